// Round 17
// baseline (99.576 us; speedup 1.0000x reference)
//
#include <hip/hip_runtime.h>
#include <hip/hip_bf16.h>

#define D_ 64
#define HW_ 4096
#define K_ 1024
#define NPTS_ 65536
#define QOUT_ 4194304      // B*D*H*W, offset of idx region in d_out
#define DELTA 0.006f       // ambiguity margin; worst-case bf16-split diff ~2e-3
#define INF_ 3.4e38f
#define NCH 32             // chunks of 32 codes (8 KB each)

typedef short bf16x8 __attribute__((ext_vector_type(8)));
typedef float f32x4 __attribute__((ext_vector_type(4)));

__device__ __forceinline__ void gload_lds16(const float* g, float* l) {
    __builtin_amdgcn_global_load_lds((const __attribute__((address_space(1))) void*)g,
                                     (__attribute__((address_space(3))) void*)l, 16, 0, 0);
}

// ---- pack kernel: cnorm + bf16 hi/lo split of (-2*cb) in MFMA-fragment order ----
// P layout (shorts): [gch(64)][frag(4)][lane(64)][8]
//   code j = gch*16 + (l&15), dims d = (frag>>1)*32 + (l>>4)*8 + i, lvl = frag&1
__global__ __launch_bounds__(256) void vq_pack(const float* __restrict__ cb,
                                               float* __restrict__ cnorm,
                                               short* __restrict__ P) {
    const int t = blockIdx.x * 256 + threadIdx.x;   // 0..4095
    const int gch = t >> 6, l = t & 63;
    const int j  = gch * 16 + (l & 15);
    const int dg = l >> 4;
#pragma unroll
    for (int s = 0; s < 2; ++s) {
        const float* src = cb + j * D_ + s * 32 + dg * 8;
        short hb[8], lb[8];
#pragma unroll
        for (int i = 0; i < 8; ++i) {
            const float v = -2.f * src[i];
            __hip_bfloat16 h = __float2bfloat16(v);
            hb[i] = *(const short*)&h;
            const float r = v - __bfloat162float(h);
            __hip_bfloat16 lo = __float2bfloat16(r);
            lb[i] = *(const short*)&lo;
        }
        short* dh = P + ((size_t)(gch * 4 + s * 2 + 0) * 64 + l) * 8;
        short* dl = P + ((size_t)(gch * 4 + s * 2 + 1) * 64 + l) * 8;
#pragma unroll
        for (int i = 0; i < 8; ++i) { dh[i] = hb[i]; dl[i] = lb[i]; }
    }
    if (t < K_) {
        const float4* r = (const float4*)(cb + (size_t)t * D_);
        float s0 = 0.f, s1 = 0.f, s2 = 0.f, s3 = 0.f;
#pragma unroll
        for (int i = 0; i < 16; ++i) {
            float4 v = r[i];
            s0 = fmaf(v.x, v.x, s0); s1 = fmaf(v.y, v.y, s1);
            s2 = fmaf(v.z, v.z, s2); s3 = fmaf(v.w, v.w, s3);
        }
        cnorm[t] = (s0 + s1) + (s2 + s3);
    }
}

// stage one 8 KB chunk (32 codes): 2 wave-rounds x 1 KB (wave-uniform dst)
__device__ __forceinline__ void stage_chunk(const float* src, float* dst,
                                            int wid, int lane) {
#pragma unroll
    for (int r = 0; r < 2; ++r)
        gload_lds16(src + (wid * 2 + r) * 256 + lane * 4,
                    dst + (wid * 2 + r) * 256);
}

// ---- fused main: 3-deep counted-vmcnt pipeline, 5 blocks/CU occupancy ----
// 512 blocks x 256 thr (4 waves x 32 pts = 128 pts). Every wave scans all
// 1024 codes. 32 chunks x 32 codes, LDS triple-buffered (24 KB) + cnt (4 KB)
// = ~29 KB -> 5 blocks/CU = 20 waves/CU (vs R16's 8). Counted s_waitcnt
// vmcnt(2): chunk c+2's loads stay in flight across every barrier (no drain).
// Tripwires: absmax != 0 -> pipeline race; WRITE >> 17 MB -> spill.
__global__ __launch_bounds__(256, 5) void vq_main(const float* __restrict__ x,
                                                  const float* __restrict__ cb,
                                                  const float* __restrict__ cnorm_g,
                                                  const short* __restrict__ P,
                                                  float* __restrict__ out) {
    __shared__ short cbuf[3][4096];    // 3 x 8 KB code buffers
    __shared__ float cnt[K_];          // 4 KB
    __shared__ int res_idx[128];
    __shared__ int flist[128];
    __shared__ int fcnt;

    const int tid  = threadIdx.x;
    const int lane = tid & 63;
    const int wid  = tid >> 6;        // 0..3 = 32-pt group
    const int pg   = blockIdx.x;      // 0..511
    const int bb   = pg >> 5;
    const int hw0  = (pg & 31) << 7;  // 128 pts per block

    if (tid == 0) fcnt = 0;

    const float* Pf = (const float*)P;
    float* buf0 = (float*)cbuf[0];
    float* buf1 = (float*)cbuf[1];
    float* buf2 = (float*)cbuf[2];

    // prologue: issue cnt (1 load/wave) + chunk0 (2) + chunk1 (2)
    gload_lds16(cnorm_g + wid * 256 + lane * 4, cnt + wid * 256);
    stage_chunk(Pf, buf0, wid, lane);
    stage_chunk(Pf + 2048, buf1, wid, lane);

    // x load + split (long; staging loads keep flying underneath)
    bf16x8 ah[2][2], al[2][2];
    {
        const float* xb = x + (size_t)bb * (D_ * HW_) + hw0;
#pragma unroll
        for (int t = 0; t < 2; ++t) {
            const int p_l = wid * 32 + t * 16 + (lane & 15);
#pragma unroll
            for (int s = 0; s < 2; ++s) {
                const int d0 = s * 32 + (lane >> 4) * 8;
#pragma unroll
                for (int i = 0; i < 8; ++i) {
                    const float v = xb[(size_t)(d0 + i) * HW_ + p_l];
                    __hip_bfloat16 h = __float2bfloat16(v);
                    ah[t][s][i] = *(const short*)&h;
                    const float r = v - __bfloat162float(h);
                    __hip_bfloat16 lo = __float2bfloat16(r);
                    al[t][s][i] = *(const short*)&lo;
                }
            }
        }
    }
    asm volatile("s_waitcnt vmcnt(2)" ::: "memory");   // cnt+chunk0 done; chunk1 flying
    __builtin_amdgcn_s_barrier();
    asm volatile("" ::: "memory");

    float m1[8], m2[8];
    int   i1[8];
#pragma unroll
    for (int q = 0; q < 8; ++q) { m1[q] = INF_; m2[q] = INF_; i1[q] = 0; }

    float* bcur = buf0;   // chunk c (landed)
    float* bnxt = buf1;   // chunk c+1 (may be in flight)
    float* bstg = buf2;   // staging dest for chunk c+2
#pragma unroll 1
    for (int c = 0; c < NCH; ++c) {
        if (c + 2 < NCH) stage_chunk(Pf + (size_t)(c + 2) * 2048, bstg, wid, lane);

        const bf16x8* fr = (const bf16x8*)bcur;
#pragma unroll
        for (int gl = 0; gl < 2; ++gl) {
            const int kc = c * 32 + gl * 16 + (lane & 15);
            const float cn = cnt[kc];
            bf16x8 bh0 = fr[(gl * 4 + 0) * 64 + lane];
            bf16x8 bl0 = fr[(gl * 4 + 1) * 64 + lane];
            bf16x8 bh1 = fr[(gl * 4 + 2) * 64 + lane];
            bf16x8 bl1 = fr[(gl * 4 + 3) * 64 + lane];
            f32x4 a0a = {0.f, 0.f, 0.f, 0.f};   // tile0, dims 0-31 (3-deep)
            f32x4 a0b = {0.f, 0.f, 0.f, 0.f};   // tile0, dims 32-63
            f32x4 a1a = {0.f, 0.f, 0.f, 0.f};   // tile1, dims 0-31
            f32x4 a1b = {0.f, 0.f, 0.f, 0.f};   // tile1, dims 32-63
            a0a = __builtin_amdgcn_mfma_f32_16x16x32_bf16(ah[0][0], bh0, a0a, 0, 0, 0);
            a1a = __builtin_amdgcn_mfma_f32_16x16x32_bf16(ah[1][0], bh0, a1a, 0, 0, 0);
            a0b = __builtin_amdgcn_mfma_f32_16x16x32_bf16(ah[0][1], bh1, a0b, 0, 0, 0);
            a1b = __builtin_amdgcn_mfma_f32_16x16x32_bf16(ah[1][1], bh1, a1b, 0, 0, 0);
            a0a = __builtin_amdgcn_mfma_f32_16x16x32_bf16(al[0][0], bh0, a0a, 0, 0, 0);
            a1a = __builtin_amdgcn_mfma_f32_16x16x32_bf16(al[1][0], bh0, a1a, 0, 0, 0);
            a0b = __builtin_amdgcn_mfma_f32_16x16x32_bf16(al[0][1], bh1, a0b, 0, 0, 0);
            a1b = __builtin_amdgcn_mfma_f32_16x16x32_bf16(al[1][1], bh1, a1b, 0, 0, 0);
            a0a = __builtin_amdgcn_mfma_f32_16x16x32_bf16(ah[0][0], bl0, a0a, 0, 0, 0);
            a1a = __builtin_amdgcn_mfma_f32_16x16x32_bf16(ah[1][0], bl0, a1a, 0, 0, 0);
            a0b = __builtin_amdgcn_mfma_f32_16x16x32_bf16(ah[0][1], bl1, a0b, 0, 0, 0);
            a1b = __builtin_amdgcn_mfma_f32_16x16x32_bf16(ah[1][1], bl1, a1b, 0, 0, 0);
#pragma unroll
            for (int t = 0; t < 2; ++t)
#pragma unroll
                for (int r = 0; r < 4; ++r) {
                    const int q = t * 4 + r;
                    const float d2 = cn + ((t == 0) ? (a0a[r] + a0b[r])
                                                    : (a1a[r] + a1b[r]));
                    const bool lt = d2 < m1[q];
                    m2[q] = fminf(m2[q], fmaxf(m1[q], d2));
                    m1[q] = fminf(m1[q], d2);
                    i1[q] = lt ? kc : i1[q];
                }
        }

        // chunk c+1 must be landed before next iter; c+2's 2 loads may fly
        if (c + 2 < NCH) asm volatile("s_waitcnt vmcnt(2)" ::: "memory");
        else             asm volatile("s_waitcnt vmcnt(0)" ::: "memory");
        __builtin_amdgcn_s_barrier();
        asm volatile("" ::: "memory");

        float* t0 = bcur; bcur = bnxt; bnxt = bstg; bstg = t0;   // rotate
    }

    // cross-lane (m1,i1,m2) reduce over the 16 lanes sharing (lane>>4)
#pragma unroll
    for (int q = 0; q < 8; ++q) {
        float a1 = m1[q], a2 = m2[q];
        int   ai = i1[q];
#pragma unroll
        for (int m = 1; m < 16; m <<= 1) {
            const float o1 = __shfl_xor(a1, m);
            const int   oi = __shfl_xor(ai, m);
            const float o2 = __shfl_xor(a2, m);
            const float nm2 = fminf(fminf(a2, o2), fmaxf(a1, o1));
            if (o1 < a1 || (o1 == a1 && oi < ai)) { a1 = o1; ai = oi; }
            a2 = nm2;
        }
        if ((lane & 15) == 0) {
            const int t = q >> 2, r = q & 3;
            const int pt = wid * 32 + t * 16 + 4 * (lane >> 4) + r;
            res_idx[pt] = ai;
            if (a2 - a1 <= DELTA) { const int p = atomicAdd(&fcnt, 1); flist[p] = pt; }
        }
    }
    __syncthreads();

    // exact fp32 rescan for ambiguous points (expected ~0.1/block)
    const int nf = fcnt;
    for (int i = wid; i < nf; i += 4) {
        const int pt = flist[i];
        const float* xr = x + (size_t)bb * (D_ * HW_) + hw0 + pt;
        float xv[D_];
#pragma unroll
        for (int d = 0; d < D_; ++d) xv[d] = xr[(size_t)d * HW_];   // wave-uniform
        float b1 = INF_; int bi = 0;
        for (int cc = 0; cc < 16; ++cc) {
            const int row = lane * 16 + cc;
            const float4* cr = (const float4*)(cb + (size_t)row * D_);
            float a0 = 0.f, a1 = 0.f, a2 = 0.f, a3 = 0.f;
#pragma unroll
            for (int g = 0; g < 16; ++g) {
                const float4 cf = cr[g];
                a0 = fmaf(xv[4 * g + 0], cf.x, a0);
                a1 = fmaf(xv[4 * g + 1], cf.y, a1);
                a2 = fmaf(xv[4 * g + 2], cf.z, a2);
                a3 = fmaf(xv[4 * g + 3], cf.w, a3);
            }
            const float dot = (a0 + a1) + (a2 + a3);
            const float d2 = fmaf(-2.f, dot, cnt[row]);
            if (d2 < b1) { b1 = d2; bi = row; }
        }
#pragma unroll
        for (int m = 1; m < 64; m <<= 1) {
            const float o1 = __shfl_xor(b1, m);
            const int   oi = __shfl_xor(bi, m);
            if (o1 < b1 || (o1 == b1 && oi < bi)) { b1 = o1; bi = oi; }
        }
        if (lane == 0) res_idx[pt] = bi;
    }
    __syncthreads();

    // idx output (float; exact for values <= 1023)
    if (tid < 128) out[(size_t)QOUT_ + pg * 128 + tid] = (float)res_idx[tid];

    // epilogue in two 64-pt halves: [64][65] tile (16.6 KB) aliases cbuf.
    // Bank math: Phase A writes (pt + 4dq + j) and Phase B reads (4g + d + j)
    // are both 2-way max = free.
    float* tile = (float*)cbuf;
    float* ob = out + (size_t)bb * (D_ * HW_) + hw0;
#pragma unroll
    for (int half = 0; half < 2; ++half) {
        // Phase A: gather winning rows, 16 lanes x 16 B = full 256 B row each
#pragma unroll
        for (int pass = 0; pass < 4; ++pass) {
            const int pl = pass * 16 + (tid >> 4);        // local pt 0..63
            const int dq = tid & 15;
            const float4 v = *(const float4*)(cb + (size_t)res_idx[half * 64 + pl] * D_ + dq * 4);
            tile[pl * 65 + dq * 4 + 0] = v.x;
            tile[pl * 65 + dq * 4 + 1] = v.y;
            tile[pl * 65 + dq * 4 + 2] = v.z;
            tile[pl * 65 + dq * 4 + 3] = v.w;
        }
        __syncthreads();
        // Phase B: 4 scalar tile reads -> one float4 store per thread-iter
#pragma unroll
        for (int it = 0; it < 4; ++it) {
            const int e = it * 256 + tid;   // 0..1023
            const int d = e >> 4;           // 0..63
            const int g = e & 15;           // float4 group within 64 pts
            float4 q;
            q.x = tile[(g * 4 + 0) * 65 + d];
            q.y = tile[(g * 4 + 1) * 65 + d];
            q.z = tile[(g * 4 + 2) * 65 + d];
            q.w = tile[(g * 4 + 3) * 65 + d];
            *(float4*)(ob + (size_t)d * HW_ + half * 64 + g * 4) = q;
        }
        __syncthreads();
    }
}

extern "C" void kernel_launch(void* const* d_in, const int* in_sizes, int n_in,
                              void* d_out, int out_size, void* d_ws, size_t ws_size,
                              hipStream_t stream) {
    const float* x  = (const float*)d_in[0];   // (16, 64, 64, 64)
    const float* cb = (const float*)d_in[1];   // (1024, 64)
    float* out   = (float*)d_out;
    float* cnorm = (float*)d_ws;                       // 4 KB
    short* P     = (short*)((char*)d_ws + 4096);       // 256 KB packed bf16 codebook

    vq_pack<<<16, 256, 0, stream>>>(cb, cnorm, P);
    vq_main<<<NPTS_ / 128, 256, 0, stream>>>(x, cb, cnorm, P, out);
}

// Round 18
// 69.680 us; speedup vs baseline: 1.4291x; 1.4291x over previous
//
#include <hip/hip_runtime.h>
#include <hip/hip_bf16.h>

#define D_ 64
#define HW_ 4096
#define K_ 1024
#define NPTS_ 65536
#define QOUT_ 4194304      // B*D*H*W, offset of idx region in d_out
#define DELTA 0.006f       // ambiguity margin; worst-case bf16-split diff ~2e-3
#define INF_ 3.4e38f
#define NCH 32             // chunks of 32 codes (8 KB each)

typedef short bf16x8 __attribute__((ext_vector_type(8)));
typedef float f32x4 __attribute__((ext_vector_type(4)));

__device__ __forceinline__ void gload_lds16(const float* g, float* l) {
    __builtin_amdgcn_global_load_lds((const __attribute__((address_space(1))) void*)g,
                                     (__attribute__((address_space(3))) void*)l, 16, 0, 0);
}

// ---- pack kernel: cnorm + bf16 hi/lo split of (-2*cb) in MFMA-fragment order ----
// P layout (shorts): [gch(64)][frag(4)][lane(64)][8]
//   code j = gch*16 + (l&15), dims d = (frag>>1)*32 + (l>>4)*8 + i, lvl = frag&1
__global__ __launch_bounds__(256) void vq_pack(const float* __restrict__ cb,
                                               float* __restrict__ cnorm,
                                               short* __restrict__ P) {
    const int t = blockIdx.x * 256 + threadIdx.x;   // 0..4095
    const int gch = t >> 6, l = t & 63;
    const int j  = gch * 16 + (l & 15);
    const int dg = l >> 4;
#pragma unroll
    for (int s = 0; s < 2; ++s) {
        const float* src = cb + j * D_ + s * 32 + dg * 8;
        short hb[8], lb[8];
#pragma unroll
        for (int i = 0; i < 8; ++i) {
            const float v = -2.f * src[i];
            __hip_bfloat16 h = __float2bfloat16(v);
            hb[i] = *(const short*)&h;
            const float r = v - __bfloat162float(h);
            __hip_bfloat16 lo = __float2bfloat16(r);
            lb[i] = *(const short*)&lo;
        }
        short* dh = P + ((size_t)(gch * 4 + s * 2 + 0) * 64 + l) * 8;
        short* dl = P + ((size_t)(gch * 4 + s * 2 + 1) * 64 + l) * 8;
#pragma unroll
        for (int i = 0; i < 8; ++i) { dh[i] = hb[i]; dl[i] = lb[i]; }
    }
    if (t < K_) {
        const float4* r = (const float4*)(cb + (size_t)t * D_);
        float s0 = 0.f, s1 = 0.f, s2 = 0.f, s3 = 0.f;
#pragma unroll
        for (int i = 0; i < 16; ++i) {
            float4 v = r[i];
            s0 = fmaf(v.x, v.x, s0); s1 = fmaf(v.y, v.y, s1);
            s2 = fmaf(v.z, v.z, s2); s3 = fmaf(v.w, v.w, s3);
        }
        cnorm[t] = (s0 + s1) + (s2 + s3);
    }
}

// stage one 8 KB chunk (32 codes): 2 wave-rounds x 1 KB (wave-uniform dst)
__device__ __forceinline__ void stage_chunk(const float* src, float* dst,
                                            int wid, int lane) {
#pragma unroll
    for (int r = 0; r < 2; ++r)
        gload_lds16(src + (wid * 2 + r) * 256 + lane * 4,
                    dst + (wid * 2 + r) * 256);
}

// ---- fused main: counted-vmcnt 3-buf pipeline at 4 waves/SIMD ----
// 1024 blocks x 256 thr (4 waves x 16 pts = 64 pts/block). Grid/256 = 4
// blocks/CU, LDS (~29.5 KB) allows 5 -> 16 waves/CU (R17 lesson: blocks/CU =
// min(LDS, VGPR, grid/256)). Every wave scans all 1024 codes in 32 chunks of
// 32 codes, triple-buffered; s_waitcnt vmcnt(2) keeps chunk c+2's loads in
// flight across every barrier (no drain -- R16's proven win).
// Tripwires: absmax != 0 -> pipeline race; WRITE >> 17 MB -> spill.
__global__ __launch_bounds__(256, 4) void vq_main(const float* __restrict__ x,
                                                  const float* __restrict__ cb,
                                                  const float* __restrict__ cnorm_g,
                                                  const short* __restrict__ P,
                                                  float* __restrict__ out) {
    __shared__ short cbuf[3][4096];    // 3 x 8 KB code buffers
    __shared__ float cnt[K_];          // 4 KB
    __shared__ int res_idx[64];
    __shared__ int flist[64];
    __shared__ int fcnt;

    const int tid  = threadIdx.x;
    const int lane = tid & 63;
    const int wid  = tid >> 6;        // 0..3 = 16-pt group
    const int pg   = blockIdx.x;      // 0..1023
    const int bb   = pg >> 6;
    const int hw0  = (pg & 63) << 6;  // 64 pts per block

    if (tid == 0) fcnt = 0;

    const float* Pf = (const float*)P;
    float* buf0 = (float*)cbuf[0];
    float* buf1 = (float*)cbuf[1];
    float* buf2 = (float*)cbuf[2];

    // prologue: issue cnt (1 load/wave) + chunk0 (2) + chunk1 (2)
    gload_lds16(cnorm_g + wid * 256 + lane * 4, cnt + wid * 256);
    stage_chunk(Pf, buf0, wid, lane);
    stage_chunk(Pf + 2048, buf1, wid, lane);

    // x load + split for this wave's 16 points (staging loads fly underneath)
    bf16x8 ah[2], al[2];
    {
        const float* xb = x + (size_t)bb * (D_ * HW_) + hw0;
        const int p_l = wid * 16 + (lane & 15);
#pragma unroll
        for (int s = 0; s < 2; ++s) {
            const int d0 = s * 32 + (lane >> 4) * 8;
#pragma unroll
            for (int i = 0; i < 8; ++i) {
                const float v = xb[(size_t)(d0 + i) * HW_ + p_l];
                __hip_bfloat16 h = __float2bfloat16(v);
                ah[s][i] = *(const short*)&h;
                const float r = v - __bfloat162float(h);
                __hip_bfloat16 lo = __float2bfloat16(r);
                al[s][i] = *(const short*)&lo;
            }
        }
    }
    asm volatile("s_waitcnt vmcnt(2)" ::: "memory");   // cnt+chunk0 done; chunk1 flying
    __builtin_amdgcn_s_barrier();
    asm volatile("" ::: "memory");

    float m1[4], m2[4];
    int   i1[4];
#pragma unroll
    for (int q = 0; q < 4; ++q) { m1[q] = INF_; m2[q] = INF_; i1[q] = 0; }

    float* bcur = buf0;   // chunk c (landed)
    float* bnxt = buf1;   // chunk c+1 (may be in flight)
    float* bstg = buf2;   // staging dest for chunk c+2
#pragma unroll 1
    for (int c = 0; c < NCH; ++c) {
        if (c + 2 < NCH) stage_chunk(Pf + (size_t)(c + 2) * 2048, bstg, wid, lane);

        const bf16x8* fr = (const bf16x8*)bcur;
#pragma unroll
        for (int gl = 0; gl < 2; ++gl) {
            const int kc = c * 32 + gl * 16 + (lane & 15);
            const float cn = cnt[kc];
            bf16x8 bh0 = fr[(gl * 4 + 0) * 64 + lane];
            bf16x8 bl0 = fr[(gl * 4 + 1) * 64 + lane];
            bf16x8 bh1 = fr[(gl * 4 + 2) * 64 + lane];
            bf16x8 bl1 = fr[(gl * 4 + 3) * 64 + lane];
            f32x4 aa = {0.f, 0.f, 0.f, 0.f};   // dims 0-31 (3-deep chain)
            f32x4 ab = {0.f, 0.f, 0.f, 0.f};   // dims 32-63 (3-deep chain)
            aa = __builtin_amdgcn_mfma_f32_16x16x32_bf16(ah[0], bh0, aa, 0, 0, 0);
            ab = __builtin_amdgcn_mfma_f32_16x16x32_bf16(ah[1], bh1, ab, 0, 0, 0);
            aa = __builtin_amdgcn_mfma_f32_16x16x32_bf16(al[0], bh0, aa, 0, 0, 0);
            ab = __builtin_amdgcn_mfma_f32_16x16x32_bf16(al[1], bh1, ab, 0, 0, 0);
            aa = __builtin_amdgcn_mfma_f32_16x16x32_bf16(ah[0], bl0, aa, 0, 0, 0);
            ab = __builtin_amdgcn_mfma_f32_16x16x32_bf16(ah[1], bl1, ab, 0, 0, 0);
#pragma unroll
            for (int r = 0; r < 4; ++r) {
                const float d2 = cn + (aa[r] + ab[r]);
                const bool lt = d2 < m1[r];
                m2[r] = fminf(m2[r], fmaxf(m1[r], d2));  // min(m2, loser)
                m1[r] = fminf(m1[r], d2);
                i1[r] = lt ? kc : i1[r];
            }
        }

        // chunk c+1 must be landed before next iter; c+2's 2 loads may fly
        if (c + 2 < NCH) asm volatile("s_waitcnt vmcnt(2)" ::: "memory");
        else             asm volatile("s_waitcnt vmcnt(0)" ::: "memory");
        __builtin_amdgcn_s_barrier();
        asm volatile("" ::: "memory");

        float* t0 = bcur; bcur = bnxt; bnxt = bstg; bstg = t0;   // rotate
    }

    // cross-lane (m1,i1,m2) reduce over the 16 lanes sharing (lane>>4)
#pragma unroll
    for (int q = 0; q < 4; ++q) {
        float a1 = m1[q], a2 = m2[q];
        int   ai = i1[q];
#pragma unroll
        for (int m = 1; m < 16; m <<= 1) {
            const float o1 = __shfl_xor(a1, m);
            const int   oi = __shfl_xor(ai, m);
            const float o2 = __shfl_xor(a2, m);
            const float nm2 = fminf(fminf(a2, o2), fmaxf(a1, o1));
            if (o1 < a1 || (o1 == a1 && oi < ai)) { a1 = o1; ai = oi; }
            a2 = nm2;
        }
        if ((lane & 15) == 0) {
            const int pt = wid * 16 + 4 * (lane >> 4) + q;
            res_idx[pt] = ai;
            if (a2 - a1 <= DELTA) { const int p = atomicAdd(&fcnt, 1); flist[p] = pt; }
        }
    }
    __syncthreads();

    // exact fp32 rescan for ambiguous points (expected ~0.05/block)
    const int nf = fcnt;
    for (int i = wid; i < nf; i += 4) {
        const int pt = flist[i];
        const float* xr = x + (size_t)bb * (D_ * HW_) + hw0 + pt;
        float xv[D_];
#pragma unroll
        for (int d = 0; d < D_; ++d) xv[d] = xr[(size_t)d * HW_];   // wave-uniform
        float b1 = INF_; int bi = 0;
        for (int cc = 0; cc < 16; ++cc) {
            const int row = lane * 16 + cc;
            const float4* cr = (const float4*)(cb + (size_t)row * D_);
            float a0 = 0.f, a1 = 0.f, a2 = 0.f, a3 = 0.f;
#pragma unroll
            for (int g = 0; g < 16; ++g) {
                const float4 cf = cr[g];
                a0 = fmaf(xv[4 * g + 0], cf.x, a0);
                a1 = fmaf(xv[4 * g + 1], cf.y, a1);
                a2 = fmaf(xv[4 * g + 2], cf.z, a2);
                a3 = fmaf(xv[4 * g + 3], cf.w, a3);
            }
            const float dot = (a0 + a1) + (a2 + a3);
            const float d2 = fmaf(-2.f, dot, cnt[row]);
            if (d2 < b1) { b1 = d2; bi = row; }
        }
#pragma unroll
        for (int m = 1; m < 64; m <<= 1) {
            const float o1 = __shfl_xor(b1, m);
            const int   oi = __shfl_xor(bi, m);
            if (o1 < b1 || (o1 == b1 && oi < bi)) { b1 = o1; bi = oi; }
        }
        if (lane == 0) res_idx[pt] = bi;
    }
    __syncthreads();

    // idx output (float; exact for values <= 1023)
    if (tid < 64) out[(size_t)QOUT_ + (pg << 6) + tid] = (float)res_idx[tid];

    // epilogue: [64][65] tile (16.6 KB) aliases cbuf. Phase A writes and
    // Phase B reads are both <= 2-way bank aliasing (free).
    float* tile = (float*)cbuf;
    // Phase A: gather winning rows, 16 lanes x 16 B = full 256 B row each
#pragma unroll
    for (int pass = 0; pass < 4; ++pass) {
        const int pl = pass * 16 + (tid >> 4);        // pt 0..63
        const int dq = tid & 15;
        const float4 v = *(const float4*)(cb + (size_t)res_idx[pl] * D_ + dq * 4);
        tile[pl * 65 + dq * 4 + 0] = v.x;
        tile[pl * 65 + dq * 4 + 1] = v.y;
        tile[pl * 65 + dq * 4 + 2] = v.z;
        tile[pl * 65 + dq * 4 + 3] = v.w;
    }
    __syncthreads();
    // Phase B: 4 scalar tile reads -> one float4 store per thread-iter
    float* ob = out + (size_t)bb * (D_ * HW_) + hw0;
#pragma unroll
    for (int it = 0; it < 4; ++it) {
        const int e = it * 256 + tid;   // 0..1023
        const int d = e >> 4;           // 0..63
        const int g = e & 15;           // float4 group within 64 pts
        float4 q;
        q.x = tile[(g * 4 + 0) * 65 + d];
        q.y = tile[(g * 4 + 1) * 65 + d];
        q.z = tile[(g * 4 + 2) * 65 + d];
        q.w = tile[(g * 4 + 3) * 65 + d];
        *(float4*)(ob + (size_t)d * HW_ + g * 4) = q;
    }
}

extern "C" void kernel_launch(void* const* d_in, const int* in_sizes, int n_in,
                              void* d_out, int out_size, void* d_ws, size_t ws_size,
                              hipStream_t stream) {
    const float* x  = (const float*)d_in[0];   // (16, 64, 64, 64)
    const float* cb = (const float*)d_in[1];   // (1024, 64)
    float* out   = (float*)d_out;
    float* cnorm = (float*)d_ws;                       // 4 KB
    short* P     = (short*)((char*)d_ws + 4096);       // 256 KB packed bf16 codebook

    vq_pack<<<16, 256, 0, stream>>>(cb, cnorm, P);
    vq_main<<<NPTS_ / 64, 256, 0, stream>>>(x, cb, cnorm, P, out);
}

// Round 19
// 61.934 us; speedup vs baseline: 1.6078x; 1.1251x over previous
//
#include <hip/hip_runtime.h>
#include <hip/hip_bf16.h>

#define D_ 64
#define HW_ 4096
#define K_ 1024
#define NPTS_ 65536
#define QOUT_ 4194304      // B*D*H*W, offset of idx region in d_out
#define DELTA 0.006f       // ambiguity margin; worst-case bf16-split diff ~2e-3
#define INF_ 3.4e38f

typedef short bf16x8 __attribute__((ext_vector_type(8)));
typedef float f32x4 __attribute__((ext_vector_type(4)));

// ---- pack kernel: cnorm + bf16 hi/lo split of (-2*cb) in MFMA-fragment order ----
// P layout (shorts): [g(64)][frag(4)][lane(64)][8]
//   code j = g*16 + (l&15), dims d = (frag>>1)*32 + (l>>4)*8 + i, lvl = frag&1
__global__ __launch_bounds__(256) void vq_pack(const float* __restrict__ cb,
                                               float* __restrict__ cnorm,
                                               short* __restrict__ P) {
    const int t = blockIdx.x * 256 + threadIdx.x;   // 0..4095
    const int gch = t >> 6, l = t & 63;
    const int j  = gch * 16 + (l & 15);
    const int dg = l >> 4;
#pragma unroll
    for (int s = 0; s < 2; ++s) {
        const float* src = cb + j * D_ + s * 32 + dg * 8;
        short hb[8], lb[8];
#pragma unroll
        for (int i = 0; i < 8; ++i) {
            const float v = -2.f * src[i];
            __hip_bfloat16 h = __float2bfloat16(v);
            hb[i] = *(const short*)&h;
            const float r = v - __bfloat162float(h);
            __hip_bfloat16 lo = __float2bfloat16(r);
            lb[i] = *(const short*)&lo;
        }
        short* dh = P + ((size_t)(gch * 4 + s * 2 + 0) * 64 + l) * 8;
        short* dl = P + ((size_t)(gch * 4 + s * 2 + 1) * 64 + l) * 8;
#pragma unroll
        for (int i = 0; i < 8; ++i) { dh[i] = hb[i]; dl[i] = lb[i]; }
    }
    if (t < K_) {
        const float4* r = (const float4*)(cb + (size_t)t * D_);
        float s0 = 0.f, s1 = 0.f, s2 = 0.f, s3 = 0.f;
#pragma unroll
        for (int i = 0; i < 16; ++i) {
            float4 v = r[i];
            s0 = fmaf(v.x, v.x, s0); s1 = fmaf(v.y, v.y, s1);
            s2 = fmaf(v.z, v.z, s2); s3 = fmaf(v.w, v.w, s3);
        }
        cnorm[t] = (s0 + s1) + (s2 + s3);
    }
}

// one 16-code group step: 12 MFMAs (R14/R16-proven chain split) + min-update
#define VQ_STEP(BH0, BL0, BH1, BL1, CN, G) do {                                   \
    const int kc_ = (G) * 16 + kl;                                                \
    f32x4 a0a = {0.f,0.f,0.f,0.f}, a0b = {0.f,0.f,0.f,0.f};                       \
    f32x4 a1a = {0.f,0.f,0.f,0.f}, a1b = {0.f,0.f,0.f,0.f};                       \
    a0a = __builtin_amdgcn_mfma_f32_16x16x32_bf16(ah[0][0], BH0, a0a, 0, 0, 0);   \
    a1a = __builtin_amdgcn_mfma_f32_16x16x32_bf16(ah[1][0], BH0, a1a, 0, 0, 0);   \
    a0b = __builtin_amdgcn_mfma_f32_16x16x32_bf16(ah[0][1], BH1, a0b, 0, 0, 0);   \
    a1b = __builtin_amdgcn_mfma_f32_16x16x32_bf16(ah[1][1], BH1, a1b, 0, 0, 0);   \
    a0a = __builtin_amdgcn_mfma_f32_16x16x32_bf16(al[0][0], BH0, a0a, 0, 0, 0);   \
    a1a = __builtin_amdgcn_mfma_f32_16x16x32_bf16(al[1][0], BH0, a1a, 0, 0, 0);   \
    a0b = __builtin_amdgcn_mfma_f32_16x16x32_bf16(al[0][1], BH1, a0b, 0, 0, 0);   \
    a1b = __builtin_amdgcn_mfma_f32_16x16x32_bf16(al[1][1], BH1, a1b, 0, 0, 0);   \
    a0a = __builtin_amdgcn_mfma_f32_16x16x32_bf16(ah[0][0], BL0, a0a, 0, 0, 0);   \
    a1a = __builtin_amdgcn_mfma_f32_16x16x32_bf16(ah[1][0], BL0, a1a, 0, 0, 0);   \
    a0b = __builtin_amdgcn_mfma_f32_16x16x32_bf16(ah[0][1], BL1, a0b, 0, 0, 0);   \
    a1b = __builtin_amdgcn_mfma_f32_16x16x32_bf16(ah[1][1], BL1, a1b, 0, 0, 0);   \
    _Pragma("unroll")                                                             \
    for (int t_ = 0; t_ < 2; ++t_)                                                \
        _Pragma("unroll")                                                         \
        for (int r_ = 0; r_ < 4; ++r_) {                                          \
            const int q_ = t_ * 4 + r_;                                           \
            const float d2_ = (CN) + ((t_ == 0) ? (a0a[r_] + a0b[r_])             \
                                                : (a1a[r_] + a1b[r_]));           \
            const bool lt_ = d2_ < m1[q_];                                        \
            m2[q_] = fminf(m2[q_], fmaxf(m1[q_], d2_));                           \
            m1[q_] = fminf(m1[q_], d2_);                                          \
            i1[q_] = lt_ ? kc_ : i1[q_];                                          \
        }                                                                         \
} while (0)

// ---- fused main: BARRIER-FREE register-pipelined global-B streaming ----
// 512 blocks x 256 thr (4 waves x 32 pts). Each wave streams all 1024 codes
// in 64 groups; explicit ping-pong prefetch (B <- g+1, compute g from A,
// A <- g+2, compute g+1 from B) forces loads to issue one full group (~300
// cyc) ahead of use -- covers L2 latency without LDS or barriers (R15's
// unroll-hint version failed: compiler sank loads; named regs fix that).
// (256,2) -> VGPR cap 256. Tripwires: VGPR ~64 = pipeline defeated;
// WRITE >> 17 MB = spill; absmax != 0 = bug.
__global__ __launch_bounds__(256, 2) void vq_main(const float* __restrict__ x,
                                                  const float* __restrict__ cb,
                                                  const float* __restrict__ cnorm_g,
                                                  const short* __restrict__ P,
                                                  float* __restrict__ out) {
    __shared__ float tile[128 * 65];   // 33.3 KB epilogue transpose staging
    __shared__ int res_idx[128];
    __shared__ int flist[128];
    __shared__ int fcnt;

    const int tid  = threadIdx.x;
    const int lane = tid & 63;
    const int wid  = tid >> 6;        // 0..3 = 32-pt group
    const int kl   = lane & 15;
    const int pg   = blockIdx.x;      // 0..511
    const int bb   = pg >> 5;
    const int hw0  = (pg & 31) << 7;  // 128 pts per block

    if (tid == 0) fcnt = 0;

    // x load + split: wave owns 32 points (two 16x16 A-tiles)
    bf16x8 ah[2][2], al[2][2];
    {
        const float* xb = x + (size_t)bb * (D_ * HW_) + hw0;
#pragma unroll
        for (int t = 0; t < 2; ++t) {
            const int p_l = wid * 32 + t * 16 + kl;
#pragma unroll
            for (int s = 0; s < 2; ++s) {
                const int d0 = s * 32 + (lane >> 4) * 8;
#pragma unroll
                for (int i = 0; i < 8; ++i) {
                    const float v = xb[(size_t)(d0 + i) * HW_ + p_l];
                    __hip_bfloat16 h = __float2bfloat16(v);
                    ah[t][s][i] = *(const short*)&h;
                    const float r = v - __bfloat162float(h);
                    __hip_bfloat16 lo = __float2bfloat16(r);
                    al[t][s][i] = *(const short*)&lo;
                }
            }
        }
    }
    __syncthreads();   // fcnt visible before flag writes

    float m1[8], m2[8];
    int   i1[8];
#pragma unroll
    for (int q = 0; q < 8; ++q) { m1[q] = INF_; m2[q] = INF_; i1[q] = 0; }

    const bf16x8* gp = (const bf16x8*)P;

    // prologue: group 0 -> A registers
    bf16x8 A0 = gp[0 * 64 + lane], A1 = gp[1 * 64 + lane];
    bf16x8 A2 = gp[2 * 64 + lane], A3 = gp[3 * 64 + lane];
    float cnA = cnorm_g[kl];
    bf16x8 B0, B1, B2, B3;
    float cnB;

#pragma unroll 1
    for (int gg = 0; gg < 32; ++gg) {
        const int g0 = gg * 2, g1 = g0 + 1, g2 = g0 + 2;
        // prefetch group g1 -> B (used after ~12 MFMA + epilogue)
        B0 = gp[(g1 * 4 + 0) * 64 + lane];
        B1 = gp[(g1 * 4 + 1) * 64 + lane];
        B2 = gp[(g1 * 4 + 2) * 64 + lane];
        B3 = gp[(g1 * 4 + 3) * 64 + lane];
        cnB = cnorm_g[g1 * 16 + kl];
        // compute group g0 from A
        VQ_STEP(A0, A1, A2, A3, cnA, g0);
        // prefetch group g2 -> A
        if (g2 < 64) {
            A0 = gp[(g2 * 4 + 0) * 64 + lane];
            A1 = gp[(g2 * 4 + 1) * 64 + lane];
            A2 = gp[(g2 * 4 + 2) * 64 + lane];
            A3 = gp[(g2 * 4 + 3) * 64 + lane];
            cnA = cnorm_g[g2 * 16 + kl];
        }
        // compute group g1 from B
        VQ_STEP(B0, B1, B2, B3, cnB, g1);
    }

    // cross-lane (m1,i1,m2) reduce over the 16 lanes sharing (lane>>4);
    // wave covered all K -> result final.
#pragma unroll
    for (int q = 0; q < 8; ++q) {
        float a1 = m1[q], a2 = m2[q];
        int   ai = i1[q];
#pragma unroll
        for (int m = 1; m < 16; m <<= 1) {
            const float o1 = __shfl_xor(a1, m);
            const int   oi = __shfl_xor(ai, m);
            const float o2 = __shfl_xor(a2, m);
            const float nm2 = fminf(fminf(a2, o2), fmaxf(a1, o1));
            if (o1 < a1 || (o1 == a1 && oi < ai)) { a1 = o1; ai = oi; }
            a2 = nm2;
        }
        if ((lane & 15) == 0) {
            const int t = q >> 2, r = q & 3;
            const int pt = wid * 32 + t * 16 + 4 * (lane >> 4) + r;
            res_idx[pt] = ai;
            if (a2 - a1 <= DELTA) { const int p = atomicAdd(&fcnt, 1); flist[p] = pt; }
        }
    }
    __syncthreads();

    // exact fp32 rescan for ambiguous points (expected ~0.1/block)
    const int nf = fcnt;
    for (int i = wid; i < nf; i += 4) {
        const int pt = flist[i];
        const float* xr = x + (size_t)bb * (D_ * HW_) + hw0 + pt;
        float xv[D_];
#pragma unroll
        for (int d = 0; d < D_; ++d) xv[d] = xr[(size_t)d * HW_];   // wave-uniform
        float b1 = INF_; int bi = 0;
        for (int cc = 0; cc < 16; ++cc) {
            const int row = lane * 16 + cc;
            const float4* cr = (const float4*)(cb + (size_t)row * D_);
            float a0 = 0.f, a1 = 0.f, a2 = 0.f, a3 = 0.f;
#pragma unroll
            for (int g = 0; g < 16; ++g) {
                const float4 cf = cr[g];
                a0 = fmaf(xv[4 * g + 0], cf.x, a0);
                a1 = fmaf(xv[4 * g + 1], cf.y, a1);
                a2 = fmaf(xv[4 * g + 2], cf.z, a2);
                a3 = fmaf(xv[4 * g + 3], cf.w, a3);
            }
            const float dot = (a0 + a1) + (a2 + a3);
            const float d2 = fmaf(-2.f, dot, cnorm_g[row]);
            if (d2 < b1) { b1 = d2; bi = row; }
        }
#pragma unroll
        for (int m = 1; m < 64; m <<= 1) {
            const float o1 = __shfl_xor(b1, m);
            const int   oi = __shfl_xor(bi, m);
            if (o1 < b1 || (o1 == b1 && oi < bi)) { b1 = o1; bi = oi; }
        }
        if (lane == 0) res_idx[pt] = bi;
    }
    __syncthreads();

    // idx output (float; exact for values <= 1023)
    if (tid < 128) out[(size_t)QOUT_ + pg * 128 + tid] = (float)res_idx[tid];

    // Phase A: gather winning rows (16 lanes x 16 B = full 256 B row each),
    // write into [pt][65] tile. Banks: pt + 4dq + j -> 2-way max (free).
#pragma unroll
    for (int pass = 0; pass < 8; ++pass) {
        const int pt = pass * 16 + (tid >> 4);
        const int dq = tid & 15;
        const float4 v = *(const float4*)(cb + (size_t)res_idx[pt] * D_ + dq * 4);
        tile[pt * 65 + dq * 4 + 0] = v.x;
        tile[pt * 65 + dq * 4 + 1] = v.y;
        tile[pt * 65 + dq * 4 + 2] = v.z;
        tile[pt * 65 + dq * 4 + 3] = v.w;
    }
    __syncthreads();

    // Phase B: 4 scalar tile reads -> one float4 store (512 B contiguous per d)
    float* ob = out + (size_t)bb * (D_ * HW_) + hw0;
#pragma unroll
    for (int it = 0; it < 8; ++it) {
        const int e = it * 256 + tid;   // 0..2047
        const int d = e >> 5;           // 0..63
        const int g = e & 31;           // float4 group within 128 pts
        float4 q;
        q.x = tile[(g * 4 + 0) * 65 + d];
        q.y = tile[(g * 4 + 1) * 65 + d];
        q.z = tile[(g * 4 + 2) * 65 + d];
        q.w = tile[(g * 4 + 3) * 65 + d];
        *(float4*)(ob + (size_t)d * HW_ + g * 4) = q;
    }
}

extern "C" void kernel_launch(void* const* d_in, const int* in_sizes, int n_in,
                              void* d_out, int out_size, void* d_ws, size_t ws_size,
                              hipStream_t stream) {
    const float* x  = (const float*)d_in[0];   // (16, 64, 64, 64)
    const float* cb = (const float*)d_in[1];   // (1024, 64)
    float* out   = (float*)d_out;
    float* cnorm = (float*)d_ws;                       // 4 KB
    short* P     = (short*)((char*)d_ws + 4096);       // 256 KB packed bf16 codebook

    vq_pack<<<16, 256, 0, stream>>>(cb, cnorm, P);
    vq_main<<<NPTS_ / 128, 256, 0, stream>>>(x, cb, cnorm, P, out);
}